// Round 3
// baseline (352.739 us; speedup 1.0000x reference)
//
#include <hip/hip_runtime.h>
#include <math.h>

#define TB 8    // BATCH
#define TT 12   // T_IN
#define HV 32   // H_VEL

typedef float v2f __attribute__((ext_vector_type(2)));

// ---------- dual-row f32 velocity branch, time-packed dots ----------
// computes sigmoid( relu(LN(x@W1^T+b1)) @ w2 + b2 ) for two rows at once
__device__ __forceinline__ void vel2_rows(
    const v2f xa[6], const v2f xb[6],
    const float* __restrict__ w1, const float* __restrict__ b1,
    const float* __restrict__ g,  const float* __restrict__ bn,
    const float* __restrict__ w2, float b2,
    float& oa, float& ob) {
  float ha[HV], hb[HV];
  float s1a = 0.f, s2a = 0.f, s1b = 0.f, s2b = 0.f;
#pragma unroll
  for (int j = 0; j < HV; ++j) {
    const float* w = w1 + j * TT;
    v2f pa = {0.f, 0.f}, pb = {0.f, 0.f};
#pragma unroll
    for (int k = 0; k < 6; ++k) {
      v2f wv = *(const v2f*)(w + 2 * k);
      pa = __builtin_elementwise_fma(xa[k], wv, pa);
      pb = __builtin_elementwise_fma(xb[k], wv, pb);
    }
    float bj  = b1[j];
    float hja = pa.x + pa.y + bj;
    float hjb = pb.x + pb.y + bj;
    ha[j] = hja; hb[j] = hjb;
    s1a += hja; s2a = fmaf(hja, hja, s2a);
    s1b += hjb; s2b = fmaf(hjb, hjb, s2b);
  }
  float mua  = s1a * (1.f/HV);
  float vara = s2a * (1.f/HV) - mua*mua;
  float inva = 1.f / sqrtf(vara + 1e-5f);
  float mub  = s1b * (1.f/HV);
  float varb = s2b * (1.f/HV) - mub*mub;
  float invb = 1.f / sqrtf(varb + 1e-5f);
  float aa = b2, ab = b2;
#pragma unroll
  for (int j = 0; j < HV; ++j) {
    float gj = g[j], bnj = bn[j], w2j = w2[j];
    float ya = fmaf((ha[j]-mua)*inva, gj, bnj);
    float yb = fmaf((hb[j]-mub)*invb, gj, bnj);
    ya = fmaxf(ya, 0.f); yb = fmaxf(yb, 0.f);
    aa = fmaf(ya, w2j, aa);
    ab = fmaf(yb, w2j, ab);
  }
  oa = 1.f / (1.f + __expf(-aa));
  ob = 1.f / (1.f + __expf(-ab));
}

// ---------- f64 velocity branch (cold path, rare; reads row from global) ----------
__device__ __noinline__ double vel_branch64(const float* x,
    const float* __restrict__ w1, const float* __restrict__ b1,
    const float* __restrict__ g,  const float* __restrict__ bn,
    const float* __restrict__ w2, float b2) {
  double s1 = 0.0, s2 = 0.0;
  for (int j = 0; j < HV; ++j) {
    double hj = (double)b1[j];
    for (int t = 0; t < TT; ++t) hj = fma((double)x[t], (double)w1[j*TT+t], hj);
    s1 += hj;
    s2 = fma(hj, hj, s2);
  }
  double mu  = s1 / (double)HV;
  double var = s2 / (double)HV - mu*mu;
  double inv = 1.0 / sqrt(var + 1e-5);
  double acc = (double)b2;
  for (int j = 0; j < HV; ++j) {
    double hj = (double)b1[j];
    for (int t = 0; t < TT; ++t) hj = fma((double)x[t], (double)w1[j*TT+t], hj);
    double yl = (hj - mu) * inv * (double)g[j] + (double)bn[j];
    if (yl < 0.0) yl = 0.0;
    acc = fma(yl, (double)w2[j], acc);
  }
  return 1.0 / (1.0 + exp(-acc));
}

// ---------- K0: zero den+pred, block 0 reduces attention scalars ----------
__global__ void __launch_bounds__(256) k_zero_prep(
    float* __restrict__ den, float* __restrict__ pred, int nb,
    const float* __restrict__ attn_w, const float* __restrict__ ln2_g,
    const float* __restrict__ ln2_b, float* __restrict__ scal) {
  int idx = blockIdx.x * blockDim.x + threadIdx.x;
  for (int i = idx; i < nb; i += gridDim.x * blockDim.x) { den[i] = 0.f; pred[i] = 0.f; }
  if (blockIdx.x == 0) {
    __shared__ float sg[256], sb[256];
    float a = 0.f, b = 0.f;
    if (threadIdx.x < 129) {
      float w = attn_w[threadIdx.x];
      a = w * ln2_g[threadIdx.x];
      b = w * ln2_b[threadIdx.x];
    }
    sg[threadIdx.x] = a; sb[threadIdx.x] = b;
    __syncthreads();
    for (int s = 128; s > 0; s >>= 1) {
      if (threadIdx.x < s) { sg[threadIdx.x] += sg[threadIdx.x+s]; sb[threadIdx.x] += sb[threadIdx.x+s]; }
      __syncthreads();
    }
    if (threadIdx.x == 0) { scal[0] = sg[0]; scal[1] = sb[0]; }
  }
}

// ---------- K1: per-(node,batch) precompute {Sz, Sz2, p_src, p_dst} ----------
__global__ void __launch_bounds__(256, 2) k_node(
    const float* __restrict__ feature, const float* __restrict__ fc_w,
    const float* __restrict__ attn_w,  const float* __restrict__ ln2_g,
    float4* __restrict__ nodepre, int n_nodes) {
  int idx = blockIdx.x * blockDim.x + threadIdx.x;
  int total = n_nodes * TB;
  if (idx >= total) return;
  const float4* f4 = (const float4*)(feature + (size_t)idx * TT);
  float4 fa = f4[0], fb = f4[1], fcv = f4[2];
  v2f xv[6] = {{fa.x,fa.y},{fa.z,fa.w},{fb.x,fb.y},{fb.z,fb.w},{fcv.x,fcv.y},{fcv.z,fcv.w}};
  float q = 0.f, r = 0.f, ps = 0.f, pd = 0.f;
#pragma unroll 8
  for (int i = 0; i < 64; ++i) {
    v2f p = {0.f, 0.f};
#pragma unroll
    for (int k = 0; k < 6; ++k)
      p = __builtin_elementwise_fma(xv[k], *(const v2f*)(fc_w + i*TT + 2*k), p);
    float z = p.x + p.y;
    q += z;
    r  = fmaf(z, z, r);
    ps = fmaf(z, attn_w[i]      * ln2_g[i],      ps);
    pd = fmaf(z, attn_w[64 + i] * ln2_g[64 + i], pd);
  }
  nodepre[idx] = make_float4(q, r, ps, pd);
}

// ---------- K2: fused edge pass, 2 batch rows per thread ----------
__global__ void __launch_bounds__(256, 3) k_edge1(
    const float* __restrict__ upstream, const float* __restrict__ downstream,
    const float* __restrict__ feature,  const float* __restrict__ distance,
    const int* __restrict__ src, const int* __restrict__ dst,
    const float* __restrict__ attn_w, const float* __restrict__ ln2_g,
    const float* __restrict__ v11_w, const float* __restrict__ v11_b,
    const float* __restrict__ ln11_g, const float* __restrict__ ln11_b,
    const float* __restrict__ v12_w, const float* __restrict__ v12_b,
    const float* __restrict__ v21_w, const float* __restrict__ v21_b,
    const float* __restrict__ ln21_g, const float* __restrict__ ln21_b,
    const float* __restrict__ v22_w, const float* __restrict__ v22_b,
    const float* __restrict__ v3_w, const float* __restrict__ v3_b,
    const float* __restrict__ alpha,
    const float4* __restrict__ nodepre, const float* __restrict__ scal,
    float2* __restrict__ epbuf, float* __restrict__ den,
    int n_pairs) {
  int idx = blockIdx.x * blockDim.x + threadIdx.x;
  if (idx >= n_pairs) return;
  int e    = idx >> 2;          // edge
  int row0 = idx * 2;           // (e, bp) flat row; row1 = row0+1
  int b0   = row0 & 7;

  // --- issue gathers early ---
  int s = src[e], d = dst[e];
  float dist = distance[e];
  float al   = alpha[e];
  const float4* f4 = (const float4*)(feature + ((size_t)s * TB + b0) * TT);
  float4 F0 = f4[0], F1 = f4[1], F2 = f4[2], F3 = f4[3], F4 = f4[4], F5 = f4[5];
  float4 nps0 = nodepre[(size_t)s * TB + b0];
  float4 nps1 = nodepre[(size_t)s * TB + b0 + 1];
  float4 npd0 = nodepre[(size_t)d * TB + b0];
  float4 npd1 = nodepre[(size_t)d * TB + b0 + 1];

  // --- upstream branch, rows a/b ---
  float xu0, xu1, xd0, xd1;
  {
    const float4* u4 = (const float4*)(upstream + (size_t)row0 * TT);
    float4 U0=u4[0],U1=u4[1],U2=u4[2],U3=u4[3],U4=u4[4],U5=u4[5];
    v2f xa[6] = {{U0.x,U0.y},{U0.z,U0.w},{U1.x,U1.y},{U1.z,U1.w},{U2.x,U2.y},{U2.z,U2.w}};
    v2f xb[6] = {{U3.x,U3.y},{U3.z,U3.w},{U4.x,U4.y},{U4.z,U4.w},{U5.x,U5.y},{U5.z,U5.w}};
    vel2_rows(xa, xb, v11_w, v11_b, ln11_g, ln11_b, v12_w, v12_b[0], xu0, xu1);
  }
  {
    const float4* d4 = (const float4*)(downstream + (size_t)row0 * TT);
    float4 D0=d4[0],D1=d4[1],D2=d4[2],D3=d4[3],D4=d4[4],D5=d4[5];
    v2f xa[6] = {{D0.x,D0.y},{D0.z,D0.w},{D1.x,D1.y},{D1.z,D1.w},{D2.x,D2.y},{D2.z,D2.w}};
    v2f xb[6] = {{D3.x,D3.y},{D3.z,D3.w},{D4.x,D4.y},{D4.z,D4.w},{D5.x,D5.y},{D5.z,D5.w}};
    vel2_rows(xa, xb, v21_w, v21_b, ln21_g, ln21_b, v22_w, v22_b[0], xd0, xd1);
  }

  float feat0[TT] = {F0.x,F0.y,F0.z,F0.w, F1.x,F1.y,F1.z,F1.w, F2.x,F2.y,F2.z,F2.w};
  float feat1[TT] = {F3.x,F3.y,F3.z,F3.w, F4.x,F4.y,F4.z,F4.w, F5.x,F5.y,F5.z,F5.w};
  float ex_r[2], pe_r[2];

#pragma unroll
  for (int r = 0; r < 2; ++r) {
    float xu = r ? xu1 : xu0;
    float xd = r ? xd1 : xd0;
    float y  = fmaf(xu, v3_w[0], fmaf(xd, v3_w[1], v3_b[0]));
    float v  = log1pf(expf(y));

    float tt  = dist / (v + 1e-5f);
    float th  = tt * 0.1f;
    float tif = rintf(th);

    // selective f64 recompute near round() boundaries (chaos control)
    if (fabsf(th - tif) < 1e-3f && tt < 120.0f) {
      const float* xr_u = upstream   + (size_t)(row0 + r) * TT;
      const float* xr_d = downstream + (size_t)(row0 + r) * TT;
      double xu64 = vel_branch64(xr_u, v11_w, v11_b, ln11_g, ln11_b, v12_w, v12_b[0]);
      double xd64 = vel_branch64(xr_d, v21_w, v21_b, ln21_g, ln21_b, v22_w, v22_b[0]);
      double y64  = xu64*(double)v3_w[0] + xd64*(double)v3_w[1] + (double)v3_b[0];
      double v64  = log1p(exp(y64));
      double tt64 = (double)dist / (v64 + 1e-5);
      v   = (float)v64;
      tt  = (float)tt64;
      tif = (float)rint(tt64 * 0.1);
    }

    int ti = (int)tif;
    ti = ti < 0 ? 0 : (ti > TT ? TT - 1 : ti);
    int n = TT - ti; n = n < 1 ? 1 : n;

    float F  = 1.f / fmaf(al, tt, 1.f);
    float om = 1.f - F;

    const float* feat = r ? feat1 : feat0;
    float pe = 0.f, w = F;
#pragma unroll
    for (int t = TT - 1; t >= 0; --t) {
      if (t < n) { pe = fmaf(w, feat[t], pe); w *= om; }
    }

    float4 nps = r ? nps1 : nps0;
    float4 npd = r ? npd1 : npd0;
    float sum   = nps.x + npd.x + v;
    float sumsq = nps.y + npd.y + v*v;
    float mu  = sum * (1.f/129.f);
    float var = sumsq * (1.f/129.f) - mu*mu;
    float S1  = nps.z + npd.w + v * attn_w[128] * ln2_g[128];
    float aa  = (S1 - mu*scal[0]) / sqrtf(var + 1e-5f) + scal[1];
    float a   = aa >= 0.f ? aa : 0.01f*aa;
    ex_r[r] = __expf(a);
    pe_r[r] = pe;
  }

  // one float4 store covers both rows' {ex, pe}
  float4 ep4 = make_float4(ex_r[0], pe_r[0], ex_r[1], pe_r[1]);
  *(float4*)(&epbuf[row0]) = ep4;
  atomicAdd(&den[s * TB + b0],     ex_r[0]);
  atomicAdd(&den[s * TB + b0 + 1], ex_r[1]);
}

// ---------- K3: normalize + scatter to pred, 2 rows per thread ----------
__global__ void __launch_bounds__(256) k_edge2(
    const int* __restrict__ src, const int* __restrict__ dst,
    const float2* __restrict__ epbuf,
    const float* __restrict__ den, float* __restrict__ pred, int n_pairs) {
  int idx = blockIdx.x * blockDim.x + threadIdx.x;
  if (idx >= n_pairs) return;
  int e    = idx >> 2;
  int row0 = idx * 2;
  int b0   = row0 & 7;
  float4 ep = *(const float4*)(&epbuf[row0]);
  int s = src[e], d = dst[e];
  float den0 = den[s * TB + b0];
  float den1 = den[s * TB + b0 + 1];
  atomicAdd(&pred[d * TB + b0],     (ep.x / den0) * ep.y);
  atomicAdd(&pred[d * TB + b0 + 1], (ep.z / den1) * ep.w);
}

extern "C" void kernel_launch(void* const* d_in, const int* in_sizes, int n_in,
                              void* d_out, int out_size, void* d_ws, size_t ws_size,
                              hipStream_t stream) {
  const float* upstream   = (const float*)d_in[0];
  const float* downstream = (const float*)d_in[1];
  const float* feature    = (const float*)d_in[2];
  const float* distance   = (const float*)d_in[3];
  const int*   src        = (const int*)d_in[4];
  const int*   dst        = (const int*)d_in[5];
  const float* fc_w   = (const float*)d_in[6];
  const float* attn_w = (const float*)d_in[7];
  const float* ln2_g  = (const float*)d_in[8];
  const float* ln2_b  = (const float*)d_in[9];
  const float* v11_w  = (const float*)d_in[10];
  const float* v11_b  = (const float*)d_in[11];
  const float* ln11_g = (const float*)d_in[12];
  const float* ln11_b = (const float*)d_in[13];
  const float* v12_w  = (const float*)d_in[14];
  const float* v12_b  = (const float*)d_in[15];
  const float* v21_w  = (const float*)d_in[16];
  const float* v21_b  = (const float*)d_in[17];
  const float* ln21_g = (const float*)d_in[18];
  const float* ln21_b = (const float*)d_in[19];
  const float* v22_w  = (const float*)d_in[20];
  const float* v22_b  = (const float*)d_in[21];
  const float* v3_w   = (const float*)d_in[22];
  const float* v3_b   = (const float*)d_in[23];
  const float* alpha  = (const float*)d_in[24];

  int E  = in_sizes[4];
  int N  = in_sizes[2] / (TB * TT);
  int NB = N * TB;
  int EB = E * TB;
  int NP = EB / 2;   // row pairs

  float*  ws      = (float*)d_ws;
  float4* nodepre = (float4*)ws;                 // 4*NB floats
  float2* epbuf   = (float2*)(ws + 4 * (size_t)NB); // 2*EB floats
  float*  den     = ws + 4 * (size_t)NB + 2 * (size_t)EB; // NB floats
  float*  scal    = den + NB;                    // 2 floats
  float*  pred    = (float*)d_out;               // NB floats

  int blk = 256;
  k_zero_prep<<<(NB + blk - 1) / blk, blk, 0, stream>>>(den, pred, NB, attn_w, ln2_g, ln2_b, scal);
  k_node<<<(NB + blk - 1) / blk, blk, 0, stream>>>(feature, fc_w, attn_w, ln2_g, nodepre, N);
  k_edge1<<<(NP + blk - 1) / blk, blk, 0, stream>>>(
      upstream, downstream, feature, distance, src, dst,
      attn_w, ln2_g,
      v11_w, v11_b, ln11_g, ln11_b, v12_w, v12_b,
      v21_w, v21_b, ln21_g, ln21_b, v22_w, v22_b,
      v3_w, v3_b, alpha,
      nodepre, scal, epbuf, den, NP);
  k_edge2<<<(NP + blk - 1) / blk, blk, 0, stream>>>(src, dst, epbuf, den, pred, NP);
}

// Round 4
// 187.630 us; speedup vs baseline: 1.8800x; 1.8800x over previous
//
#include <hip/hip_runtime.h>
#include <math.h>

#define TB 8    // BATCH
#define TT 12   // T_IN
#define HV 32   // H_VEL

typedef float v2f __attribute__((ext_vector_type(2)));

// ---------- f32 velocity branch, t-packed dots + j-paired LN tail ----------
// sigmoid( relu(LN(x@W1^T + b1)) @ w2 + b2 ), one row
__device__ __forceinline__ float vel_branch32(const v2f xv[6],
    const float* __restrict__ w1, const float* __restrict__ b1,
    const float* __restrict__ g,  const float* __restrict__ bn,
    const float* __restrict__ w2, float b2) {
  v2f h2[HV/2];
  v2f s1v = {0.f, 0.f}, s2v = {0.f, 0.f};
#pragma unroll
  for (int jp = 0; jp < HV/2; ++jp) {
    const float* w0 = w1 + (2*jp)   * TT;
    const float* w1r = w1 + (2*jp+1) * TT;
    v2f p0 = {0.f, 0.f}, p1 = {0.f, 0.f};
#pragma unroll
    for (int k = 0; k < 6; ++k) {
      p0 = __builtin_elementwise_fma(xv[k], *(const v2f*)(w0  + 2*k), p0);
      p1 = __builtin_elementwise_fma(xv[k], *(const v2f*)(w1r + 2*k), p1);
    }
    v2f bj = *(const v2f*)(b1 + 2*jp);
    v2f hv = {p0.x + p0.y + bj.x, p1.x + p1.y + bj.y};
    h2[jp] = hv;
    s1v += hv;
    s2v = __builtin_elementwise_fma(hv, hv, s2v);
  }
  float s1 = s1v.x + s1v.y;
  float s2 = s2v.x + s2v.y;
  float mu  = s1 * (1.f/HV);
  float var = s2 * (1.f/HV) - mu*mu;
  float inv = 1.f / sqrtf(var + 1e-5f);
  v2f mu2  = {mu, mu};
  v2f inv2 = {inv, inv};
  v2f zero = {0.f, 0.f};
  v2f acc2 = {b2, 0.f};
#pragma unroll
  for (int jp = 0; jp < HV/2; ++jp) {
    v2f gv  = *(const v2f*)(g  + 2*jp);
    v2f bnv = *(const v2f*)(bn + 2*jp);
    v2f w2v = *(const v2f*)(w2 + 2*jp);
    v2f yl = __builtin_elementwise_fma((h2[jp] - mu2) * inv2, gv, bnv);
    yl = __builtin_elementwise_max(yl, zero);
    acc2 = __builtin_elementwise_fma(yl, w2v, acc2);
  }
  float acc = acc2.x + acc2.y;
  return 1.f / (1.f + __expf(-acc));
}

// ---------- f64 velocity branch (cold path, rare; reads row from global) ----------
__device__ __noinline__ double vel_branch64(const float* x,
    const float* __restrict__ w1, const float* __restrict__ b1,
    const float* __restrict__ g,  const float* __restrict__ bn,
    const float* __restrict__ w2, float b2) {
  double s1 = 0.0, s2 = 0.0;
  for (int j = 0; j < HV; ++j) {
    double hj = (double)b1[j];
    for (int t = 0; t < TT; ++t) hj = fma((double)x[t], (double)w1[j*TT+t], hj);
    s1 += hj;
    s2 = fma(hj, hj, s2);
  }
  double mu  = s1 / (double)HV;
  double var = s2 / (double)HV - mu*mu;
  double inv = 1.0 / sqrt(var + 1e-5);
  double acc = (double)b2;
  for (int j = 0; j < HV; ++j) {
    double hj = (double)b1[j];
    for (int t = 0; t < TT; ++t) hj = fma((double)x[t], (double)w1[j*TT+t], hj);
    double yl = (hj - mu) * inv * (double)g[j] + (double)bn[j];
    if (yl < 0.0) yl = 0.0;
    acc = fma(yl, (double)w2[j], acc);
  }
  return 1.0 / (1.0 + exp(-acc));
}

// ---------- K0: zero den+pred, block 0 reduces attention scalars ----------
__global__ void __launch_bounds__(256) k_zero_prep(
    float* __restrict__ den, float* __restrict__ pred, int nb,
    const float* __restrict__ attn_w, const float* __restrict__ ln2_g,
    const float* __restrict__ ln2_b, float* __restrict__ scal) {
  int idx = blockIdx.x * blockDim.x + threadIdx.x;
  for (int i = idx; i < nb; i += gridDim.x * blockDim.x) { den[i] = 0.f; pred[i] = 0.f; }
  if (blockIdx.x == 0) {
    __shared__ float sg[256], sb[256];
    float a = 0.f, b = 0.f;
    if (threadIdx.x < 129) {
      float w = attn_w[threadIdx.x];
      a = w * ln2_g[threadIdx.x];
      b = w * ln2_b[threadIdx.x];
    }
    sg[threadIdx.x] = a; sb[threadIdx.x] = b;
    __syncthreads();
    for (int s = 128; s > 0; s >>= 1) {
      if (threadIdx.x < s) { sg[threadIdx.x] += sg[threadIdx.x+s]; sb[threadIdx.x] += sb[threadIdx.x+s]; }
      __syncthreads();
    }
    if (threadIdx.x == 0) { scal[0] = sg[0]; scal[1] = sb[0]; }
  }
}

// ---------- K1: per-(node,batch) precompute {Sz, Sz2, p_src, p_dst} ----------
__global__ void __launch_bounds__(256, 2) k_node(
    const float* __restrict__ feature, const float* __restrict__ fc_w,
    const float* __restrict__ attn_w,  const float* __restrict__ ln2_g,
    float4* __restrict__ nodepre, int n_nodes) {
  int idx = blockIdx.x * blockDim.x + threadIdx.x;
  int total = n_nodes * TB;
  if (idx >= total) return;
  const float4* f4 = (const float4*)(feature + (size_t)idx * TT);
  float4 fa = f4[0], fb = f4[1], fcv = f4[2];
  v2f xv[6] = {{fa.x,fa.y},{fa.z,fa.w},{fb.x,fb.y},{fb.z,fb.w},{fcv.x,fcv.y},{fcv.z,fcv.w}};
  float q = 0.f, r = 0.f, ps = 0.f, pd = 0.f;
#pragma unroll 8
  for (int i = 0; i < 64; ++i) {
    v2f p = {0.f, 0.f};
#pragma unroll
    for (int k = 0; k < 6; ++k)
      p = __builtin_elementwise_fma(xv[k], *(const v2f*)(fc_w + i*TT + 2*k), p);
    float z = p.x + p.y;
    q += z;
    r  = fmaf(z, z, r);
    ps = fmaf(z, attn_w[i]      * ln2_g[i],      ps);
    pd = fmaf(z, attn_w[64 + i] * ln2_g[64 + i], pd);
  }
  nodepre[idx] = make_float4(q, r, ps, pd);
}

// ---------- K2: fused edge pass, 1 (edge,batch) row per thread ----------
__global__ void __launch_bounds__(256, 2) k_edge1(
    const float* __restrict__ upstream, const float* __restrict__ downstream,
    const float* __restrict__ feature,  const float* __restrict__ distance,
    const int* __restrict__ src, const int* __restrict__ dst,
    const float* __restrict__ attn_w, const float* __restrict__ ln2_g,
    const float* __restrict__ v11_w, const float* __restrict__ v11_b,
    const float* __restrict__ ln11_g, const float* __restrict__ ln11_b,
    const float* __restrict__ v12_w, const float* __restrict__ v12_b,
    const float* __restrict__ v21_w, const float* __restrict__ v21_b,
    const float* __restrict__ ln21_g, const float* __restrict__ ln21_b,
    const float* __restrict__ v22_w, const float* __restrict__ v22_b,
    const float* __restrict__ v3_w, const float* __restrict__ v3_b,
    const float* __restrict__ alpha,
    const float4* __restrict__ nodepre, const float* __restrict__ scal,
    float2* __restrict__ epbuf, float* __restrict__ den,
    int n_edges) {
  int idx = blockIdx.x * blockDim.x + threadIdx.x;
  if (idx >= n_edges * TB) return;
  int e = idx >> 3, b = idx & 7;

  // --- issue all random gathers early (latency hides under MLP compute) ---
  int s = src[e], d = dst[e];
  float dist = distance[e];
  float al   = alpha[e];
  const float4* f4 = (const float4*)(feature + ((size_t)s * TB + b) * TT);
  float4 f0 = f4[0], f1 = f4[1], f2 = f4[2];
  float4 nps = nodepre[(size_t)s * TB + b];
  float4 npd = nodepre[(size_t)d * TB + b];

  float xu, xd;
  {
    const float4* u4 = (const float4*)(upstream + (size_t)idx * TT);
    float4 a0 = u4[0], a1 = u4[1], a2 = u4[2];
    v2f xv[6] = {{a0.x,a0.y},{a0.z,a0.w},{a1.x,a1.y},{a1.z,a1.w},{a2.x,a2.y},{a2.z,a2.w}};
    xu = vel_branch32(xv, v11_w, v11_b, ln11_g, ln11_b, v12_w, v12_b[0]);
  }
  {
    const float4* d4 = (const float4*)(downstream + (size_t)idx * TT);
    float4 c0 = d4[0], c1 = d4[1], c2 = d4[2];
    v2f xv[6] = {{c0.x,c0.y},{c0.z,c0.w},{c1.x,c1.y},{c1.z,c1.w},{c2.x,c2.y},{c2.z,c2.w}};
    xd = vel_branch32(xv, v21_w, v21_b, ln21_g, ln21_b, v22_w, v22_b[0]);
  }
  float y = fmaf(xu, v3_w[0], fmaf(xd, v3_w[1], v3_b[0]));
  // softplus via hardware exp/log: log1p(e^y) = max(y,0) + log(1 + e^-|y|)
  float v = fmaxf(y, 0.f) + __logf(1.f + __expf(-fabsf(y)));

  float tt  = dist / (v + 1e-5f);
  float th  = tt * 0.1f;
  float tif = rintf(th);

  // --- selective f64 recompute near round() boundaries (chaos control) ---
  if (fabsf(th - tif) < 1e-3f && tt < 120.0f) {
    const float* xr_u = upstream   + (size_t)idx * TT;
    const float* xr_d = downstream + (size_t)idx * TT;
    double xu64 = vel_branch64(xr_u, v11_w, v11_b, ln11_g, ln11_b, v12_w, v12_b[0]);
    double xd64 = vel_branch64(xr_d, v21_w, v21_b, ln21_g, ln21_b, v22_w, v22_b[0]);
    double y64  = xu64*(double)v3_w[0] + xd64*(double)v3_w[1] + (double)v3_b[0];
    double v64  = log1p(exp(y64));
    double tt64 = (double)dist / (v64 + 1e-5);
    v   = (float)v64;
    tt  = (float)tt64;
    tif = (float)rint(tt64 * 0.1);
  }

  int ti = (int)tif;
  ti = ti < 0 ? 0 : (ti > TT ? TT - 1 : ti);
  int n = TT - ti; n = n < 1 ? 1 : n;

  float F  = 1.f / fmaf(al, tt, 1.f);
  float om = 1.f - F;

  // --- diffusion-weighted feature dot, Horner form:
  // pe = F * (((feat[0]*om + feat[1])*om + ...) over t < n)
  float feat[TT] = {f0.x,f0.y,f0.z,f0.w, f1.x,f1.y,f1.z,f1.w, f2.x,f2.y,f2.z,f2.w};
  float acc = 0.f;
#pragma unroll
  for (int t = 0; t < TT; ++t) {
    acc = (t < n) ? fmaf(acc, om, feat[t]) : acc;
  }
  float pe = F * acc;

  // --- attention logit via collapsed LN+dot ---
  float sum   = nps.x + npd.x + v;
  float sumsq = nps.y + npd.y + v*v;
  float mu  = sum * (1.f/129.f);
  float var = sumsq * (1.f/129.f) - mu*mu;
  float S1  = nps.z + npd.w + v * attn_w[128] * ln2_g[128];
  float aa  = (S1 - mu*scal[0]) / sqrtf(var + 1e-5f) + scal[1];
  float a   = aa >= 0.f ? aa : 0.01f*aa;
  float ex  = __expf(a);

  epbuf[idx] = make_float2(ex, pe);
  atomicAdd(&den[s * TB + b], ex);
}

// ---------- K3: normalize + scatter to pred ----------
__global__ void __launch_bounds__(256) k_edge2(
    const int* __restrict__ src, const int* __restrict__ dst,
    const float2* __restrict__ epbuf,
    const float* __restrict__ den, float* __restrict__ pred, int n_edges) {
  int idx = blockIdx.x * blockDim.x + threadIdx.x;
  if (idx >= n_edges * TB) return;
  int e = idx >> 3, b = idx & 7;
  float2 ep = epbuf[idx];
  float score = ep.x / den[src[e] * TB + b];
  atomicAdd(&pred[dst[e] * TB + b], score * ep.y);
}

extern "C" void kernel_launch(void* const* d_in, const int* in_sizes, int n_in,
                              void* d_out, int out_size, void* d_ws, size_t ws_size,
                              hipStream_t stream) {
  const float* upstream   = (const float*)d_in[0];
  const float* downstream = (const float*)d_in[1];
  const float* feature    = (const float*)d_in[2];
  const float* distance   = (const float*)d_in[3];
  const int*   src        = (const int*)d_in[4];
  const int*   dst        = (const int*)d_in[5];
  const float* fc_w   = (const float*)d_in[6];
  const float* attn_w = (const float*)d_in[7];
  const float* ln2_g  = (const float*)d_in[8];
  const float* ln2_b  = (const float*)d_in[9];
  const float* v11_w  = (const float*)d_in[10];
  const float* v11_b  = (const float*)d_in[11];
  const float* ln11_g = (const float*)d_in[12];
  const float* ln11_b = (const float*)d_in[13];
  const float* v12_w  = (const float*)d_in[14];
  const float* v12_b  = (const float*)d_in[15];
  const float* v21_w  = (const float*)d_in[16];
  const float* v21_b  = (const float*)d_in[17];
  const float* ln21_g = (const float*)d_in[18];
  const float* ln21_b = (const float*)d_in[19];
  const float* v22_w  = (const float*)d_in[20];
  const float* v22_b  = (const float*)d_in[21];
  const float* v3_w   = (const float*)d_in[22];
  const float* v3_b   = (const float*)d_in[23];
  const float* alpha  = (const float*)d_in[24];

  int E  = in_sizes[4];
  int N  = in_sizes[2] / (TB * TT);
  int NB = N * TB;
  int EB = E * TB;

  float*  ws      = (float*)d_ws;
  float4* nodepre = (float4*)ws;                 // 4*NB floats
  float2* epbuf   = (float2*)(ws + 4 * (size_t)NB); // 2*EB floats
  float*  den     = ws + 4 * (size_t)NB + 2 * (size_t)EB; // NB floats
  float*  scal    = den + NB;                    // 2 floats
  float*  pred    = (float*)d_out;               // NB floats

  int blk = 256;
  k_zero_prep<<<(NB + blk - 1) / blk, blk, 0, stream>>>(den, pred, NB, attn_w, ln2_g, ln2_b, scal);
  k_node<<<(NB + blk - 1) / blk, blk, 0, stream>>>(feature, fc_w, attn_w, ln2_g, nodepre, N);
  k_edge1<<<(EB + blk - 1) / blk, blk, 0, stream>>>(
      upstream, downstream, feature, distance, src, dst,
      attn_w, ln2_g,
      v11_w, v11_b, ln11_g, ln11_b, v12_w, v12_b,
      v21_w, v21_b, ln21_g, ln21_b, v22_w, v22_b,
      v3_w, v3_b, alpha,
      nodepre, scal, epbuf, den, E);
  k_edge2<<<(EB + blk - 1) / blk, blk, 0, stream>>>(src, dst, epbuf, den, pred, E);
}